// Round 1
// baseline (748.333 us; speedup 1.0000x reference)
//
#include <hip/hip_runtime.h>

#define N_VOXELS 150000
#define NP 60000
#define NK 27
#define CIN 32
#define COUT 64
#define BN_EPS 1e-5f
#define NELEM (N_VOXELS * COUT)

// ---------------------------------------------------------------------------
// Kernel 1: rulebook scatter conv. blockIdx.y = k (27), each wave (64 lanes)
// handles pairs in a grid-stride loop; lane = output channel. Weight column
// W[k][c][lane], c=0..31 is preloaded into 32 VGPRs per lane (once per block).
// Per pair: broadcast-load the 32-float feature row as 8x float4, 32 FMAs,
// one atomicAdd per lane (64 consecutive floats -> coalesced atomics).
// ---------------------------------------------------------------------------
__global__ __launch_bounds__(256, 6) void conv_scatter(
    const float* __restrict__ features,
    const int* __restrict__ in_idx,
    const int* __restrict__ out_idx,
    const float* __restrict__ weight,
    float* __restrict__ accum)
{
    const int k    = blockIdx.y;
    const int lane = threadIdx.x & 63;
    const int wid  = threadIdx.x >> 6;              // wave within block (0..3)
    const int gw   = blockIdx.x * 4 + wid;          // global wave id for this k
    const int nw   = gridDim.x * 4;

    // Preload this lane's weight column: w[c] = weight[k][c][lane]
    float w[CIN];
    const float* wk = weight + (size_t)k * (CIN * COUT) + lane;
#pragma unroll
    for (int c = 0; c < CIN; ++c) w[c] = wk[c * COUT];

    const int* ii = in_idx  + k * NP;
    const int* oi = out_idx + k * NP;

    for (int p = gw; p < NP; p += nw) {
        const int vin  = ii[p];   // wave-uniform (broadcast load)
        const int vout = oi[p];
        const float4* f4p = reinterpret_cast<const float4*>(features + (size_t)vin * CIN);
        float s0 = 0.f, s1 = 0.f, s2 = 0.f, s3 = 0.f;
#pragma unroll
        for (int q = 0; q < CIN / 4; ++q) {
            float4 v = f4p[q];
            s0 = fmaf(v.x, w[4 * q + 0], s0);
            s1 = fmaf(v.y, w[4 * q + 1], s1);
            s2 = fmaf(v.z, w[4 * q + 2], s2);
            s3 = fmaf(v.w, w[4 * q + 3], s3);
        }
        atomicAdd(&accum[(size_t)vout * COUT + lane], (s0 + s1) + (s2 + s3));
    }
}

// ---------------------------------------------------------------------------
// Kernel 2: per-channel batch stats of y = relu(x + bias). Read-only pass.
// channel = tid % 64 is constant per thread (stride is a multiple of 64).
// Block LDS reduce (4 threads per channel) -> 128 atomics per block.
// ---------------------------------------------------------------------------
__global__ __launch_bounds__(256) void bias_relu_stats(
    const float* __restrict__ buf,
    const float* __restrict__ bias,
    float* __restrict__ stats)   // stats[0..63]=sum, stats[64..127]=sumsq
{
    const int tid    = blockIdx.x * 256 + threadIdx.x;
    const int stride = gridDim.x * 256;
    const int c      = threadIdx.x & 63;
    const float b    = bias[c];

    float sum = 0.f, sumsq = 0.f;
    for (int i = tid; i < NELEM; i += stride) {
        float y = buf[i] + b;
        y = fmaxf(y, 0.f);
        sum += y;
        sumsq += y * y;
    }

    __shared__ float ls[256];
    __shared__ float lq[256];
    ls[threadIdx.x] = sum;
    lq[threadIdx.x] = sumsq;
    __syncthreads();
    if (threadIdx.x < 64) {
        float s = ls[threadIdx.x] + ls[threadIdx.x + 64] +
                  ls[threadIdx.x + 128] + ls[threadIdx.x + 192];
        float q = lq[threadIdx.x] + lq[threadIdx.x + 64] +
                  lq[threadIdx.x + 128] + lq[threadIdx.x + 192];
        atomicAdd(&stats[c], s);
        atomicAdd(&stats[64 + c], q);
    }
}

// ---------------------------------------------------------------------------
// Kernel 3: recompute y = relu(x + bias), apply BN with batch stats, in place.
// ---------------------------------------------------------------------------
__global__ __launch_bounds__(256) void bn_apply(
    float* __restrict__ buf,
    const float* __restrict__ bias,
    const float* __restrict__ stats,
    const float* __restrict__ gamma,
    const float* __restrict__ beta)
{
    const int c = threadIdx.x & 63;
    const float inv_n = 1.f / (float)N_VOXELS;
    const float mean  = stats[c] * inv_n;
    const float var   = stats[64 + c] * inv_n - mean * mean;
    const float scale = gamma[c] * rsqrtf(var + BN_EPS);
    const float shift = beta[c] - mean * scale;
    const float b     = bias[c];

    const int tid    = blockIdx.x * 256 + threadIdx.x;
    const int stride = gridDim.x * 256;
    for (int i = tid; i < NELEM; i += stride) {
        float y = fmaxf(buf[i] + b, 0.f);
        buf[i] = fmaf(y, scale, shift);
    }
}

extern "C" void kernel_launch(void* const* d_in, const int* in_sizes, int n_in,
                              void* d_out, int out_size, void* d_ws, size_t ws_size,
                              hipStream_t stream) {
    const float* features = (const float*)d_in[0];
    const int*   in_idx   = (const int*)d_in[1];
    const int*   out_idx  = (const int*)d_in[2];
    const float* weight   = (const float*)d_in[3];
    const float* bias     = (const float*)d_in[4];
    const float* gamma    = (const float*)d_in[5];
    const float* beta     = (const float*)d_in[6];
    float* out   = (float*)d_out;
    float* stats = (float*)d_ws;   // 128 floats

    // Zero the accumulator (d_out) and the stats scratch.
    hipMemsetAsync(d_out, 0, (size_t)out_size * sizeof(float), stream);
    hipMemsetAsync(d_ws, 0, 128 * sizeof(float), stream);

    // Scatter conv: 27 k-slices x 76 blocks x 4 waves.
    dim3 cgrid(76, NK);
    conv_scatter<<<cgrid, 256, 0, stream>>>(features, in_idx, out_idx, weight, out);

    // Batch stats (grid kept moderate to bound atomic contention on 128 addrs).
    bias_relu_stats<<<256, 256, 0, stream>>>(out, bias, stats);

    // Apply bias+ReLU+BN in place.
    bn_apply<<<2048, 256, 0, stream>>>(out, bias, stats, gamma, beta);
}